// Round 1
// baseline (839.300 us; speedup 1.0000x reference)
//
#include <hip/hip_runtime.h>
#include <hip/hip_bf16.h>

// 5-layer GCN: out = relu( D^-1/2 (A+I) D^-1/2 (x W_l) + b_l ), repeated 5x.
// N=50000, E=800000, D=128.
//
// Pipeline per call (graph-capture safe, everything rebuilt each call):
//   1. cnt[i]=0
//   2. cnt[dst[e]]++  (atomic)                      -> in-degree (excl self)
//   3. dinv[i] = rsqrt(cnt[i]+1)                    -> incl self-loop
//   4. exclusive scan cnt -> offs/cursor (1 block)
//   5. CSR fill: p=cursor[dst]++; col[p]=src; wgt[p]=dinv[src]
//   6. 5x: gemm (h = x @ W_l), agg (out = relu(dinv_i*(sum + dinv_i*h_i)+b))

#define GCN_DIM 128
#define TILE_M 32

__global__ void init_kernel(int* __restrict__ cnt, int n) {
    int i = blockIdx.x * 256 + threadIdx.x;
    if (i < n) cnt[i] = 0;
}

__global__ void count_kernel(const int* __restrict__ dst, int* __restrict__ cnt, int E) {
    int e = blockIdx.x * 256 + threadIdx.x;
    if (e < E) atomicAdd(&cnt[dst[e]], 1);
}

__global__ void dinv_kernel(const int* __restrict__ cnt, float* __restrict__ dinv, int n) {
    int i = blockIdx.x * 256 + threadIdx.x;
    if (i < n) dinv[i] = rsqrtf((float)cnt[i] + 1.0f);
}

// Single-block scan, 1024 threads, 4 elems/thread per chunk (13 chunks @ n=50000).
__global__ void scan_kernel(const int* __restrict__ cnt, int* __restrict__ offs,
                            int* __restrict__ cursor, int n) {
    __shared__ int buf[1024];
    __shared__ int carry_s;
    int tid = threadIdx.x;
    if (tid == 0) carry_s = 0;
    __syncthreads();
    const int CHUNK = 4096;
    int nch = (n + CHUNK - 1) / CHUNK;
    for (int ch = 0; ch < nch; ch++) {
        int i0 = ch * CHUNK + tid * 4;
        int v0 = (i0 + 0 < n) ? cnt[i0 + 0] : 0;
        int v1 = (i0 + 1 < n) ? cnt[i0 + 1] : 0;
        int v2 = (i0 + 2 < n) ? cnt[i0 + 2] : 0;
        int v3 = (i0 + 3 < n) ? cnt[i0 + 3] : 0;
        int tsum = v0 + v1 + v2 + v3;
        buf[tid] = tsum;
        __syncthreads();
        for (int d = 1; d < 1024; d <<= 1) {
            int u = (tid >= d) ? buf[tid - d] : 0;
            __syncthreads();
            buf[tid] += u;
            __syncthreads();
        }
        int base = carry_s + buf[tid] - tsum;  // exclusive prefix for this thread's 4
        if (i0 + 0 < n) { offs[i0 + 0] = base; cursor[i0 + 0] = base; } base += v0;
        if (i0 + 1 < n) { offs[i0 + 1] = base; cursor[i0 + 1] = base; } base += v1;
        if (i0 + 2 < n) { offs[i0 + 2] = base; cursor[i0 + 2] = base; } base += v2;
        if (i0 + 3 < n) { offs[i0 + 3] = base; cursor[i0 + 3] = base; }
        __syncthreads();
        if (tid == 1023) carry_s = carry_s + buf[1023];
        __syncthreads();
    }
    if (tid == 0) offs[n] = carry_s;
}

__global__ void fill_kernel(const int* __restrict__ src, const int* __restrict__ dst,
                            const float* __restrict__ dinv, int* __restrict__ cursor,
                            int* __restrict__ col, float* __restrict__ wgt, int E) {
    int e = blockIdx.x * 256 + threadIdx.x;
    if (e < E) {
        int d = dst[e];
        int s = src[e];
        int p = atomicAdd(&cursor[d], 1);
        col[p] = s;
        wgt[p] = dinv[s];
    }
}

// h[32 rows x 128 cols per block] = x @ W.  W rows read coalesced (L2-hot),
// x tile transposed in LDS (broadcast reads), 4x4 register blocking.
__global__ __launch_bounds__(256) void gemm_kernel(const float* __restrict__ x,
                                                   const float* __restrict__ W,
                                                   float* __restrict__ h, int n) {
    __shared__ float xT[GCN_DIM][36];  // [k][r], pad 36 keeps float4 reads aligned
    int tid = threadIdx.x;
    int row0 = blockIdx.x * TILE_M;
    for (int i = tid; i < TILE_M * 32; i += 256) {
        int r = i >> 5;
        int kc = (i & 31) << 2;
        int gr = row0 + r;
        float4 v = make_float4(0.f, 0.f, 0.f, 0.f);
        if (gr < n) v = *(const float4*)&x[(size_t)gr * GCN_DIM + kc];
        xT[kc + 0][r] = v.x;
        xT[kc + 1][r] = v.y;
        xT[kc + 2][r] = v.z;
        xT[kc + 3][r] = v.w;
    }
    __syncthreads();
    int tx = tid & 31, ty = tid >> 5;
    int c0 = tx << 2, r0 = ty << 2;
    float acc[4][4] = {{0.f}};
#pragma unroll 4
    for (int k = 0; k < GCN_DIM; k++) {
        float4 wv = *(const float4*)&W[k * GCN_DIM + c0];
        float4 xv = *(const float4*)&xT[k][r0];
        acc[0][0] = fmaf(xv.x, wv.x, acc[0][0]);
        acc[0][1] = fmaf(xv.x, wv.y, acc[0][1]);
        acc[0][2] = fmaf(xv.x, wv.z, acc[0][2]);
        acc[0][3] = fmaf(xv.x, wv.w, acc[0][3]);
        acc[1][0] = fmaf(xv.y, wv.x, acc[1][0]);
        acc[1][1] = fmaf(xv.y, wv.y, acc[1][1]);
        acc[1][2] = fmaf(xv.y, wv.z, acc[1][2]);
        acc[1][3] = fmaf(xv.y, wv.w, acc[1][3]);
        acc[2][0] = fmaf(xv.z, wv.x, acc[2][0]);
        acc[2][1] = fmaf(xv.z, wv.y, acc[2][1]);
        acc[2][2] = fmaf(xv.z, wv.z, acc[2][2]);
        acc[2][3] = fmaf(xv.z, wv.w, acc[2][3]);
        acc[3][0] = fmaf(xv.w, wv.x, acc[3][0]);
        acc[3][1] = fmaf(xv.w, wv.y, acc[3][1]);
        acc[3][2] = fmaf(xv.w, wv.z, acc[3][2]);
        acc[3][3] = fmaf(xv.w, wv.w, acc[3][3]);
    }
#pragma unroll
    for (int r = 0; r < 4; r++) {
        int gr = row0 + r0 + r;
        if (gr < n) {
            float4 o = make_float4(acc[r][0], acc[r][1], acc[r][2], acc[r][3]);
            *(float4*)&h[(size_t)gr * GCN_DIM + c0] = o;
        }
    }
}

// One wave per node; lane owns 2 features (float2 -> 512B coalesced row reads).
__global__ void agg_kernel(const float* __restrict__ h, const int* __restrict__ col,
                           const float* __restrict__ wgt, const int* __restrict__ offs,
                           const float* __restrict__ dinv, const float* __restrict__ bias,
                           float* __restrict__ out, int n) {
    int gtid = blockIdx.x * blockDim.x + threadIdx.x;
    int node = gtid >> 6;
    int lane = gtid & 63;
    if (node >= n) return;
    float di = dinv[node];
    int c = lane << 1;
    float2 hv = *(const float2*)&h[(size_t)node * GCN_DIM + c];
    float ax = di * hv.x;
    float ay = di * hv.y;
    int s = offs[node], e = offs[node + 1];
    for (int j = s; j < e; j++) {
        int src = col[j];
        float w = wgt[j];
        float2 v = *(const float2*)&h[(size_t)src * GCN_DIM + c];
        ax = fmaf(w, v.x, ax);
        ay = fmaf(w, v.y, ay);
    }
    float2 b = *(const float2*)&bias[c];
    float ox = fmaf(di, ax, b.x);
    float oy = fmaf(di, ay, b.y);
    float2 r;
    r.x = fmaxf(ox, 0.f);
    r.y = fmaxf(oy, 0.f);
    *(float2*)&out[(size_t)node * GCN_DIM + c] = r;
}

extern "C" void kernel_launch(void* const* d_in, const int* in_sizes, int n_in,
                              void* d_out, int out_size, void* d_ws, size_t ws_size,
                              hipStream_t stream) {
    const float* x0   = (const float*)d_in[0];
    const int*   edges = (const int*)d_in[1];   // [2, E] int32: src then dst
    const float* Wall = (const float*)d_in[2];  // [L, 128, 128]
    const float* Ball = (const float*)d_in[3];  // [L, 128]
    float* out = (float*)d_out;

    const int n = in_sizes[0] / GCN_DIM;              // 50000
    const int E = in_sizes[1] / 2;                    // 800000
    const int L = in_sizes[2] / (GCN_DIM * GCN_DIM);  // 5

    // workspace layout (4B elements)
    int*   cnt    = (int*)d_ws;                  // n
    float* dinv   = (float*)(cnt + n);           // n
    int*   offs   = (int*)(dinv + n);            // n+1 (padded to n+16)
    int*   cursor = offs + n + 16;               // n
    int*   col    = cursor + n;                  // E
    float* wgt    = (float*)(col + E);           // E
    float* h      = wgt + E;                     // n*128
    float* xb     = h + (size_t)n * GCN_DIM;     // n*128

    const int* src = edges;
    const int* dst = edges + E;

    int nb_n = (n + 255) / 256;
    int nb_e = (E + 255) / 256;

    init_kernel<<<nb_n, 256, 0, stream>>>(cnt, n);
    count_kernel<<<nb_e, 256, 0, stream>>>(dst, cnt, E);
    dinv_kernel<<<nb_n, 256, 0, stream>>>(cnt, dinv, n);
    scan_kernel<<<1, 1024, 0, stream>>>(cnt, offs, cursor, n);
    fill_kernel<<<nb_e, 256, 0, stream>>>(src, dst, dinv, cursor, col, wgt, E);

    int gemm_blocks = (n + TILE_M - 1) / TILE_M;
    int agg_blocks  = (n + 3) / 4;  // 4 waves (nodes) per 256-thread block

    for (int l = 0; l < L; l++) {
        const float* xin = (l == 0) ? x0 : xb;
        float* o = (l == L - 1) ? out : xb;
        gemm_kernel<<<gemm_blocks, 256, 0, stream>>>(xin, Wall + (size_t)l * GCN_DIM * GCN_DIM, h, n);
        agg_kernel<<<agg_blocks, 256, 0, stream>>>(h, col, wgt, offs, dinv, Ball + (size_t)l * GCN_DIM, o, n);
    }
}

// Round 2
// 654.213 us; speedup vs baseline: 1.2829x; 1.2829x over previous
//
#include <hip/hip_runtime.h>
#include <hip/hip_bf16.h>

// 5-layer GCN: out = relu( D^-1/2 (A+I) D^-1/2 (x W_l) + b_l ), repeated 5x.
// N=50000, E=800000, D=128.
//
// R2 change: h (the per-layer GEMM output, consumed by the random-gather
// aggregation) is stored as bf16. GEMM accumulates fp32 and rounds once on
// store; aggregation unpacks to fp32 and accumulates fp32. This halves the
// gather bytes (512B -> 256B per row), the dominant cost (R1: 5x93us, 227MB
// fetch/dispatch, VALUBusy 12.8%). Inter-layer x stays fp32.

#define GCN_DIM 128
#define TILE_M 32

__device__ __forceinline__ unsigned short f2bf(float f) {
    unsigned int u = __float_as_uint(f);
    u += 0x7FFFu + ((u >> 16) & 1u);  // round-to-nearest-even
    return (unsigned short)(u >> 16);
}

__global__ void init_kernel(int* __restrict__ cnt, int n) {
    int i = blockIdx.x * 256 + threadIdx.x;
    if (i < n) cnt[i] = 0;
}

__global__ void count_kernel(const int* __restrict__ dst, int* __restrict__ cnt, int E) {
    int e = blockIdx.x * 256 + threadIdx.x;
    if (e < E) atomicAdd(&cnt[dst[e]], 1);
}

__global__ void dinv_kernel(const int* __restrict__ cnt, float* __restrict__ dinv, int n) {
    int i = blockIdx.x * 256 + threadIdx.x;
    if (i < n) dinv[i] = rsqrtf((float)cnt[i] + 1.0f);
}

// Single-block scan, 1024 threads, 4 elems/thread per chunk (13 chunks @ n=50000).
__global__ void scan_kernel(const int* __restrict__ cnt, int* __restrict__ offs,
                            int* __restrict__ cursor, int n) {
    __shared__ int buf[1024];
    __shared__ int carry_s;
    int tid = threadIdx.x;
    if (tid == 0) carry_s = 0;
    __syncthreads();
    const int CHUNK = 4096;
    int nch = (n + CHUNK - 1) / CHUNK;
    for (int ch = 0; ch < nch; ch++) {
        int i0 = ch * CHUNK + tid * 4;
        int v0 = (i0 + 0 < n) ? cnt[i0 + 0] : 0;
        int v1 = (i0 + 1 < n) ? cnt[i0 + 1] : 0;
        int v2 = (i0 + 2 < n) ? cnt[i0 + 2] : 0;
        int v3 = (i0 + 3 < n) ? cnt[i0 + 3] : 0;
        int tsum = v0 + v1 + v2 + v3;
        buf[tid] = tsum;
        __syncthreads();
        for (int d = 1; d < 1024; d <<= 1) {
            int u = (tid >= d) ? buf[tid - d] : 0;
            __syncthreads();
            buf[tid] += u;
            __syncthreads();
        }
        int base = carry_s + buf[tid] - tsum;  // exclusive prefix for this thread's 4
        if (i0 + 0 < n) { offs[i0 + 0] = base; cursor[i0 + 0] = base; } base += v0;
        if (i0 + 1 < n) { offs[i0 + 1] = base; cursor[i0 + 1] = base; } base += v1;
        if (i0 + 2 < n) { offs[i0 + 2] = base; cursor[i0 + 2] = base; } base += v2;
        if (i0 + 3 < n) { offs[i0 + 3] = base; cursor[i0 + 3] = base; }
        __syncthreads();
        if (tid == 1023) carry_s = carry_s + buf[1023];
        __syncthreads();
    }
    if (tid == 0) offs[n] = carry_s;
}

__global__ void fill_kernel(const int* __restrict__ src, const int* __restrict__ dst,
                            const float* __restrict__ dinv, int* __restrict__ cursor,
                            int* __restrict__ col, float* __restrict__ wgt, int E) {
    int e = blockIdx.x * 256 + threadIdx.x;
    if (e < E) {
        int d = dst[e];
        int s = src[e];
        int p = atomicAdd(&cursor[d], 1);
        col[p] = s;
        wgt[p] = dinv[s];
    }
}

// h[32 rows x 128 cols per block] = x @ W, fp32 accumulate, bf16 store.
__global__ __launch_bounds__(256) void gemm_kernel(const float* __restrict__ x,
                                                   const float* __restrict__ W,
                                                   unsigned short* __restrict__ h, int n) {
    __shared__ float xT[GCN_DIM][36];  // [k][r], pad 36 keeps float4 reads aligned
    int tid = threadIdx.x;
    int row0 = blockIdx.x * TILE_M;
    for (int i = tid; i < TILE_M * 32; i += 256) {
        int r = i >> 5;
        int kc = (i & 31) << 2;
        int gr = row0 + r;
        float4 v = make_float4(0.f, 0.f, 0.f, 0.f);
        if (gr < n) v = *(const float4*)&x[(size_t)gr * GCN_DIM + kc];
        xT[kc + 0][r] = v.x;
        xT[kc + 1][r] = v.y;
        xT[kc + 2][r] = v.z;
        xT[kc + 3][r] = v.w;
    }
    __syncthreads();
    int tx = tid & 31, ty = tid >> 5;
    int c0 = tx << 2, r0 = ty << 2;
    float acc[4][4] = {{0.f}};
#pragma unroll 4
    for (int k = 0; k < GCN_DIM; k++) {
        float4 wv = *(const float4*)&W[k * GCN_DIM + c0];
        float4 xv = *(const float4*)&xT[k][r0];
        acc[0][0] = fmaf(xv.x, wv.x, acc[0][0]);
        acc[0][1] = fmaf(xv.x, wv.y, acc[0][1]);
        acc[0][2] = fmaf(xv.x, wv.z, acc[0][2]);
        acc[0][3] = fmaf(xv.x, wv.w, acc[0][3]);
        acc[1][0] = fmaf(xv.y, wv.x, acc[1][0]);
        acc[1][1] = fmaf(xv.y, wv.y, acc[1][1]);
        acc[1][2] = fmaf(xv.y, wv.z, acc[1][2]);
        acc[1][3] = fmaf(xv.y, wv.w, acc[1][3]);
        acc[2][0] = fmaf(xv.z, wv.x, acc[2][0]);
        acc[2][1] = fmaf(xv.z, wv.y, acc[2][1]);
        acc[2][2] = fmaf(xv.z, wv.z, acc[2][2]);
        acc[2][3] = fmaf(xv.z, wv.w, acc[2][3]);
        acc[3][0] = fmaf(xv.w, wv.x, acc[3][0]);
        acc[3][1] = fmaf(xv.w, wv.y, acc[3][1]);
        acc[3][2] = fmaf(xv.w, wv.z, acc[3][2]);
        acc[3][3] = fmaf(xv.w, wv.w, acc[3][3]);
    }
#pragma unroll
    for (int r = 0; r < 4; r++) {
        int gr = row0 + r0 + r;
        if (gr < n) {
            ushort4 o;
            o.x = f2bf(acc[r][0]);
            o.y = f2bf(acc[r][1]);
            o.z = f2bf(acc[r][2]);
            o.w = f2bf(acc[r][3]);
            *(ushort4*)&h[(size_t)gr * GCN_DIM + c0] = o;
        }
    }
}

// One wave per node; lane owns 2 bf16 features (4B/lane -> 256B coalesced row
// reads). fp32 accumulate, fp32 output. Edge loop unrolled x2 for MLP.
__global__ void agg_kernel(const unsigned short* __restrict__ h,
                           const int* __restrict__ col,
                           const float* __restrict__ wgt, const int* __restrict__ offs,
                           const float* __restrict__ dinv, const float* __restrict__ bias,
                           float* __restrict__ out, int n) {
    int gtid = blockIdx.x * blockDim.x + threadIdx.x;
    int node = gtid >> 6;
    int lane = gtid & 63;
    if (node >= n) return;
    float di = dinv[node];
    // self-loop row (streaming across waves)
    unsigned int sp = ((const unsigned int*)(h + ((size_t)node << 7)))[lane];
    float ax = di * __uint_as_float(sp << 16);
    float ay = di * __uint_as_float(sp & 0xFFFF0000u);
    int s = offs[node], e = offs[node + 1];
    int j = s;
    for (; j + 1 < e; j += 2) {
        int s0 = col[j], s1 = col[j + 1];
        float w0 = wgt[j], w1 = wgt[j + 1];
        unsigned int p0 = ((const unsigned int*)(h + ((size_t)s0 << 7)))[lane];
        unsigned int p1 = ((const unsigned int*)(h + ((size_t)s1 << 7)))[lane];
        ax = fmaf(w0, __uint_as_float(p0 << 16), ax);
        ay = fmaf(w0, __uint_as_float(p0 & 0xFFFF0000u), ay);
        ax = fmaf(w1, __uint_as_float(p1 << 16), ax);
        ay = fmaf(w1, __uint_as_float(p1 & 0xFFFF0000u), ay);
    }
    if (j < e) {
        int s0 = col[j];
        float w0 = wgt[j];
        unsigned int p0 = ((const unsigned int*)(h + ((size_t)s0 << 7)))[lane];
        ax = fmaf(w0, __uint_as_float(p0 << 16), ax);
        ay = fmaf(w0, __uint_as_float(p0 & 0xFFFF0000u), ay);
    }
    int c = lane << 1;
    float2 b = *(const float2*)&bias[c];
    float2 r;
    r.x = fmaxf(fmaf(di, ax, b.x), 0.f);
    r.y = fmaxf(fmaf(di, ay, b.y), 0.f);
    *(float2*)&out[(size_t)node * GCN_DIM + c] = r;
}

extern "C" void kernel_launch(void* const* d_in, const int* in_sizes, int n_in,
                              void* d_out, int out_size, void* d_ws, size_t ws_size,
                              hipStream_t stream) {
    const float* x0    = (const float*)d_in[0];
    const int*   edges = (const int*)d_in[1];   // [2, E] int32: src then dst
    const float* Wall  = (const float*)d_in[2]; // [L, 128, 128]
    const float* Ball  = (const float*)d_in[3]; // [L, 128]
    float* out = (float*)d_out;

    const int n = in_sizes[0] / GCN_DIM;              // 50000
    const int E = in_sizes[1] / 2;                    // 800000
    const int L = in_sizes[2] / (GCN_DIM * GCN_DIM);  // 5

    // workspace layout (4B elements unless noted)
    int*   cnt    = (int*)d_ws;                  // n
    float* dinv   = (float*)(cnt + n);           // n
    int*   offs   = (int*)(dinv + n);            // n+1 (padded to n+16)
    int*   cursor = offs + n + 16;               // n
    int*   col    = cursor + n;                  // E
    float* wgt    = (float*)(col + E);           // E
    unsigned short* h = (unsigned short*)(wgt + E);      // n*128 bf16
    float* xb     = (float*)(h + (size_t)n * GCN_DIM);   // n*128 fp32

    const int* src = edges;
    const int* dst = edges + E;

    int nb_n = (n + 255) / 256;
    int nb_e = (E + 255) / 256;

    init_kernel<<<nb_n, 256, 0, stream>>>(cnt, n);
    count_kernel<<<nb_e, 256, 0, stream>>>(dst, cnt, E);
    dinv_kernel<<<nb_n, 256, 0, stream>>>(cnt, dinv, n);
    scan_kernel<<<1, 1024, 0, stream>>>(cnt, offs, cursor, n);
    fill_kernel<<<nb_e, 256, 0, stream>>>(src, dst, dinv, cursor, col, wgt, E);

    int gemm_blocks = (n + TILE_M - 1) / TILE_M;
    int agg_blocks  = (n + 3) / 4;  // 4 waves (nodes) per 256-thread block

    for (int l = 0; l < L; l++) {
        const float* xin = (l == 0) ? x0 : xb;
        float* o = (l == L - 1) ? out : xb;
        gemm_kernel<<<gemm_blocks, 256, 0, stream>>>(xin, Wall + (size_t)l * GCN_DIM * GCN_DIM, h, n);
        agg_kernel<<<agg_blocks, 256, 0, stream>>>(h, col, wgt, offs, dinv, Ball + (size_t)l * GCN_DIM, o, n);
    }
}

// Round 3
// 590.260 us; speedup vs baseline: 1.4219x; 1.1083x over previous
//
#include <hip/hip_runtime.h>
#include <hip/hip_bf16.h>

// 5-layer GCN: out = relu( D^-1/2 (A+I) D^-1/2 (x W_l) + b_l ), x5.
// N=50000, E=800000, D=128.
//
// R3: (1) GEMM -> MFMA bf16 with hi/lo split (x=xh+xl, W=Wh+Wl; 3 products
//     xh*Wh + xl*Wh + xh*Wl keeps fp32-level accuracy), agg hands off x as
//     bf16 hi/lo pair (same bytes as fp32). W pre-split+transposed so B
//     fragments are contiguous 16B loads.
//     (2) agg edge loop unroll x4, dual accumulators -> 4 gathers in flight
//     (R2 showed latency-bound: 43 cyc/gather vs ~18 BW floor).
//     (3) single-block scan -> 3-kernel hierarchical scan.

#define GCN_DIM 128
#define TILE_M 32

typedef short bf16x8 __attribute__((ext_vector_type(8)));
typedef float f32x4 __attribute__((ext_vector_type(4)));

__device__ __forceinline__ unsigned short f2bf(float f) {
    unsigned int u = __float_as_uint(f);
    u += 0x7FFFu + ((u >> 16) & 1u);  // RTNE
    return (unsigned short)(u >> 16);
}
__device__ __forceinline__ float bf2f(unsigned short b) {
    return __uint_as_float(((unsigned int)b) << 16);
}

__global__ void init_kernel(int* __restrict__ cnt, int n) {
    int i = blockIdx.x * 256 + threadIdx.x;
    if (i < n) cnt[i] = 0;
}

__global__ void count_kernel(const int* __restrict__ dst, int* __restrict__ cnt, int E) {
    int e = blockIdx.x * 256 + threadIdx.x;
    if (e < E) atomicAdd(&cnt[dst[e]], 1);
}

__global__ void dinv_kernel(const int* __restrict__ cnt, float* __restrict__ dinv, int n) {
    int i = blockIdx.x * 256 + threadIdx.x;
    if (i < n) dinv[i] = rsqrtf((float)cnt[i] + 1.0f);
}

// ---- hierarchical scan: part (49 blocks) -> top (1 block) -> add ----
__global__ __launch_bounds__(256) void scan_part_kernel(const int* __restrict__ cnt,
                                                        int* __restrict__ loc,   // = offs, temp
                                                        int* __restrict__ bsum, int n) {
    __shared__ int s[256];
    int t = threadIdx.x;
    int i0 = blockIdx.x * 1024 + t * 4;
    int v0 = (i0 + 0 < n) ? cnt[i0 + 0] : 0;
    int v1 = (i0 + 1 < n) ? cnt[i0 + 1] : 0;
    int v2 = (i0 + 2 < n) ? cnt[i0 + 2] : 0;
    int v3 = (i0 + 3 < n) ? cnt[i0 + 3] : 0;
    int tsum = v0 + v1 + v2 + v3;
    s[t] = tsum;
    __syncthreads();
    for (int d = 1; d < 256; d <<= 1) {
        int u = (t >= d) ? s[t - d] : 0;
        __syncthreads();
        s[t] += u;
        __syncthreads();
    }
    int base = s[t] - tsum;  // local exclusive
    if (i0 + 0 < n) loc[i0 + 0] = base; base += v0;
    if (i0 + 1 < n) loc[i0 + 1] = base; base += v1;
    if (i0 + 2 < n) loc[i0 + 2] = base; base += v2;
    if (i0 + 3 < n) loc[i0 + 3] = base;
    if (t == 255) bsum[blockIdx.x] = s[255];
}

__global__ __launch_bounds__(256) void scan_top_kernel(int* __restrict__ bsum, int nb) {
    __shared__ int s[256];
    int t = threadIdx.x;
    int v = (t < nb) ? bsum[t] : 0;
    s[t] = v;
    __syncthreads();
    for (int d = 1; d < 256; d <<= 1) {
        int u = (t >= d) ? s[t - d] : 0;
        __syncthreads();
        s[t] += u;
        __syncthreads();
    }
    if (t < nb) bsum[t] = s[t] - v;  // exclusive
}

__global__ void scan_add_kernel(int* __restrict__ offs, int* __restrict__ cursor,
                                const int* __restrict__ bsum, int n, int E) {
    int i = blockIdx.x * 256 + threadIdx.x;
    if (i < n) {
        int off = offs[i] + bsum[i >> 10];
        offs[i] = off;
        cursor[i] = off;
    }
    if (i == 0) offs[n] = E;
}

__global__ void fill_kernel(const int* __restrict__ src, const int* __restrict__ dst,
                            const float* __restrict__ dinv, int* __restrict__ cursor,
                            int* __restrict__ col, float* __restrict__ wgt, int E) {
    int e = blockIdx.x * 256 + threadIdx.x;
    if (e < E) {
        int d = dst[e];
        int s = src[e];
        int p = atomicAdd(&cursor[d], 1);
        col[p] = s;
        wgt[p] = dinv[s];
    }
}

// x0 fp32 -> (xh, xl) bf16 pair. 4 elems/thread.
__global__ void split_x_kernel(const float* __restrict__ x, unsigned short* __restrict__ xh,
                               unsigned short* __restrict__ xl, int total) {
    int i = (blockIdx.x * 256 + threadIdx.x) * 4;
    if (i >= total) return;
    float4 v = *(const float4*)&x[i];
    ushort4 h4, l4;
    h4.x = f2bf(v.x); l4.x = f2bf(v.x - bf2f(h4.x));
    h4.y = f2bf(v.y); l4.y = f2bf(v.y - bf2f(h4.y));
    h4.z = f2bf(v.z); l4.z = f2bf(v.z - bf2f(h4.z));
    h4.w = f2bf(v.w); l4.w = f2bf(v.w - bf2f(h4.w));
    *(ushort4*)&xh[i] = h4;
    *(ushort4*)&xl[i] = l4;
}

// All 5 layers' W [k][n] fp32 -> WhT/WlT [l][n][k] bf16 (transposed).
__global__ void wsplit_kernel(const float* __restrict__ Wall, unsigned short* __restrict__ WhT,
                              unsigned short* __restrict__ WlT, int total) {
    int idx = blockIdx.x * 256 + threadIdx.x;
    if (idx >= total) return;
    int l = idx >> 14;           // /16384
    int rem = idx & 16383;
    int k = rem >> 7;
    int nn = rem & 127;
    float v = Wall[idx];
    unsigned short hi = f2bf(v);
    unsigned short lo = f2bf(v - bf2f(hi));
    int o = (l << 14) + (nn << 7) + k;
    WhT[o] = hi;
    WlT[o] = lo;
}

// MFMA GEMM: h[n x 128] = (xh+xl) @ (Wh+Wl), bf16 store.
// Block = 256 (4 waves), each wave: 16 rows x 128 cols = 8 n-tiles of
// 16x16x32 MFMA, K=128 in 4 steps. 3 products: xh*Wh + xl*Wh + xh*Wl.
// A layout: m=lane&15, k=quad*8+j (contiguous 16B). B from WT[n][k]: 16B.
// C/D: col=lane&15, row=quad*4+reg.
__global__ __launch_bounds__(256) void gemm_mfma_kernel(
    const unsigned short* __restrict__ xh, const unsigned short* __restrict__ xl,
    const unsigned short* __restrict__ WhT, const unsigned short* __restrict__ WlT,
    unsigned short* __restrict__ h, int n) {
    int tid = threadIdx.x;
    int wave = tid >> 6, lane = tid & 63;
    int q = lane >> 4, ln = lane & 15;
    int rowbase = blockIdx.x * 64 + wave * 16;
    int ar = rowbase + ln;
    if (ar >= n) ar = n - 1;  // clamp; stores are guarded
    f32x4 acc[8];
#pragma unroll
    for (int t = 0; t < 8; t++) acc[t] = (f32x4)(0.f);
#pragma unroll
    for (int ks = 0; ks < 4; ks++) {
        int ka = ks * 32 + q * 8;
        bf16x8 ah = *(const bf16x8*)&xh[(size_t)ar * 128 + ka];
        bf16x8 al = *(const bf16x8*)&xl[(size_t)ar * 128 + ka];
#pragma unroll
        for (int t = 0; t < 8; t++) {
            bf16x8 bh = *(const bf16x8*)&WhT[(size_t)(t * 16 + ln) * 128 + ka];
            bf16x8 bl = *(const bf16x8*)&WlT[(size_t)(t * 16 + ln) * 128 + ka];
            acc[t] = __builtin_amdgcn_mfma_f32_16x16x32_bf16(ah, bh, acc[t], 0, 0, 0);
            acc[t] = __builtin_amdgcn_mfma_f32_16x16x32_bf16(al, bh, acc[t], 0, 0, 0);
            acc[t] = __builtin_amdgcn_mfma_f32_16x16x32_bf16(ah, bl, acc[t], 0, 0, 0);
        }
    }
#pragma unroll
    for (int t = 0; t < 8; t++) {
#pragma unroll
        for (int r = 0; r < 4; r++) {
            int row = rowbase + q * 4 + r;
            if (row < n) h[(size_t)row * 128 + t * 16 + ln] = f2bf(acc[t][r]);
        }
    }
}

// One wave per node; lane owns 2 bf16 features (4B/lane gathers). Unroll x4,
// dual accumulators -> 4 gathers in flight. Writes bf16 hi/lo pair (mid
// layers) or fp32 (final layer).
__global__ void agg_kernel(const unsigned short* __restrict__ h,
                           const int* __restrict__ col,
                           const float* __restrict__ wgt, const int* __restrict__ offs,
                           const float* __restrict__ dinv, const float* __restrict__ bias,
                           unsigned short* __restrict__ xh_out,
                           unsigned short* __restrict__ xl_out,
                           float* __restrict__ fout, int n) {
    int gtid = blockIdx.x * blockDim.x + threadIdx.x;
    int node = gtid >> 6;
    int lane = gtid & 63;
    if (node >= n) return;
    float di = dinv[node];
    unsigned int sp = ((const unsigned int*)(h + ((size_t)node << 7)))[lane];
    float ax0 = di * __uint_as_float(sp << 16);
    float ay0 = di * __uint_as_float(sp & 0xFFFF0000u);
    float ax1 = 0.f, ay1 = 0.f;
    int s = offs[node], e = offs[node + 1];
    int j = s;
    for (; j + 4 <= e; j += 4) {
        int c0 = col[j], c1 = col[j + 1], c2 = col[j + 2], c3 = col[j + 3];
        float w0 = wgt[j], w1 = wgt[j + 1], w2 = wgt[j + 2], w3 = wgt[j + 3];
        unsigned int p0 = ((const unsigned int*)(h + ((size_t)c0 << 7)))[lane];
        unsigned int p1 = ((const unsigned int*)(h + ((size_t)c1 << 7)))[lane];
        unsigned int p2 = ((const unsigned int*)(h + ((size_t)c2 << 7)))[lane];
        unsigned int p3 = ((const unsigned int*)(h + ((size_t)c3 << 7)))[lane];
        ax0 = fmaf(w0, __uint_as_float(p0 << 16), ax0);
        ay0 = fmaf(w0, __uint_as_float(p0 & 0xFFFF0000u), ay0);
        ax1 = fmaf(w1, __uint_as_float(p1 << 16), ax1);
        ay1 = fmaf(w1, __uint_as_float(p1 & 0xFFFF0000u), ay1);
        ax0 = fmaf(w2, __uint_as_float(p2 << 16), ax0);
        ay0 = fmaf(w2, __uint_as_float(p2 & 0xFFFF0000u), ay0);
        ax1 = fmaf(w3, __uint_as_float(p3 << 16), ax1);
        ay1 = fmaf(w3, __uint_as_float(p3 & 0xFFFF0000u), ay1);
    }
    for (; j < e; j++) {
        int c0 = col[j];
        float w0 = wgt[j];
        unsigned int p0 = ((const unsigned int*)(h + ((size_t)c0 << 7)))[lane];
        ax0 = fmaf(w0, __uint_as_float(p0 << 16), ax0);
        ay0 = fmaf(w0, __uint_as_float(p0 & 0xFFFF0000u), ay0);
    }
    float ax = ax0 + ax1, ay = ay0 + ay1;
    int c = lane << 1;
    float2 b = *(const float2*)&bias[c];
    float rx = fmaxf(fmaf(di, ax, b.x), 0.f);
    float ry = fmaxf(fmaf(di, ay, b.y), 0.f);
    if (fout) {
        float2 r = make_float2(rx, ry);
        *(float2*)&fout[((size_t)node << 7) + c] = r;
    } else {
        ushort2 hh, ll;
        hh.x = f2bf(rx); ll.x = f2bf(rx - bf2f(hh.x));
        hh.y = f2bf(ry); ll.y = f2bf(ry - bf2f(hh.y));
        *(ushort2*)&xh_out[((size_t)node << 7) + c] = hh;
        *(ushort2*)&xl_out[((size_t)node << 7) + c] = ll;
    }
}

extern "C" void kernel_launch(void* const* d_in, const int* in_sizes, int n_in,
                              void* d_out, int out_size, void* d_ws, size_t ws_size,
                              hipStream_t stream) {
    const float* x0    = (const float*)d_in[0];
    const int*   edges = (const int*)d_in[1];   // [2, E] int32: src then dst
    const float* Wall  = (const float*)d_in[2]; // [L, 128, 128]
    const float* Ball  = (const float*)d_in[3]; // [L, 128]
    float* out = (float*)d_out;

    const int n = in_sizes[0] / GCN_DIM;              // 50000
    const int E = in_sizes[1] / 2;                    // 800000
    const int L = in_sizes[2] / (GCN_DIM * GCN_DIM);  // 5

    // workspace layout
    int*   cnt    = (int*)d_ws;                        // n
    float* dinv   = (float*)(cnt + n);                 // n
    int*   offs   = (int*)(dinv + n);                  // n+16
    int*   cursor = offs + n + 16;                     // n
    int*   bsum   = cursor + n;                        // 64
    int*   col    = bsum + 64;                         // E
    float* wgt    = (float*)(col + E);                 // E
    unsigned short* h   = (unsigned short*)(wgt + E);  // n*128 bf16
    unsigned short* xh  = h  + (size_t)n * GCN_DIM;    // n*128 bf16
    unsigned short* xl  = xh + (size_t)n * GCN_DIM;    // n*128 bf16
    unsigned short* WhT = xl + (size_t)n * GCN_DIM;    // L*128*128 bf16
    unsigned short* WlT = WhT + (size_t)L * GCN_DIM * GCN_DIM;

    const int* src = edges;
    const int* dst = edges + E;

    int nb_n = (n + 255) / 256;
    int nb_e = (E + 255) / 256;
    int nb_scan = (n + 1023) / 1024;

    init_kernel<<<nb_n, 256, 0, stream>>>(cnt, n);
    count_kernel<<<nb_e, 256, 0, stream>>>(dst, cnt, E);
    dinv_kernel<<<nb_n, 256, 0, stream>>>(cnt, dinv, n);
    scan_part_kernel<<<nb_scan, 256, 0, stream>>>(cnt, offs, bsum, n);
    scan_top_kernel<<<1, 256, 0, stream>>>(bsum, nb_scan);
    scan_add_kernel<<<nb_n, 256, 0, stream>>>(offs, cursor, bsum, n, E);
    fill_kernel<<<nb_e, 256, 0, stream>>>(src, dst, dinv, cursor, col, wgt, E);

    int xtotal = n * GCN_DIM;
    split_x_kernel<<<(xtotal / 4 + 255) / 256, 256, 0, stream>>>(x0, xh, xl, xtotal);
    int wtotal = L * GCN_DIM * GCN_DIM;
    wsplit_kernel<<<(wtotal + 255) / 256, 256, 0, stream>>>(Wall, WhT, WlT, wtotal);

    int gemm_blocks = (n + 63) / 64;
    int agg_blocks  = (n + 3) / 4;  // 4 waves (nodes) per 256-thread block

    for (int l = 0; l < L; l++) {
        gemm_mfma_kernel<<<gemm_blocks, 256, 0, stream>>>(
            xh, xl, WhT + (size_t)l * GCN_DIM * GCN_DIM, WlT + (size_t)l * GCN_DIM * GCN_DIM, h, n);
        agg_kernel<<<agg_blocks, 256, 0, stream>>>(
            h, col, wgt, offs, dinv, Ball + (size_t)l * GCN_DIM,
            xh, xl, (l == L - 1) ? out : nullptr, n);
    }
}

// Round 5
// 520.117 us; speedup vs baseline: 1.6137x; 1.1349x over previous
//
#include <hip/hip_runtime.h>
#include <hip/hip_bf16.h>

// 5-layer GCN: out = relu( D^-1/2 (A+I) D^-1/2 (x W_l) + b_l ), x5.
// N=50000, E=800000, D=128.
//
// R5: R4 with the wsplit layer-stride bug fixed (l<<4 -> l<<5: fragment
// group index t*4+ks spans 32 values, so layer stride is 32 groups; R4's
// l*16 made layers overlap -> corrupted weights for layers 1-4).
// R4 changes under test:
//   (1) gemm: W hi/lo pre-permuted to MFMA B-fragment order, staged in
//       64KB LDS per block (R3 B-frag global loads were L2-latency-bound).
//   (2) agg: 32-feature slices, slice = blockIdx%4 (XCD-pinning attempt);
//       byte-neutral (one 64B line per edge per slice) if mapping fails.
//   (3) fill: packed (col,wgt) int2 stores.

#define GCN_DIM 128

typedef short bf16x8 __attribute__((ext_vector_type(8)));
typedef float f32x4 __attribute__((ext_vector_type(4)));

__device__ __forceinline__ unsigned short f2bf(float f) {
    unsigned int u = __float_as_uint(f);
    u += 0x7FFFu + ((u >> 16) & 1u);  // RTNE
    return (unsigned short)(u >> 16);
}
__device__ __forceinline__ float bf2f(unsigned short b) {
    return __uint_as_float(((unsigned int)b) << 16);
}
__device__ __forceinline__ float bflo(unsigned int p) { return __uint_as_float(p << 16); }
__device__ __forceinline__ float bfhi(unsigned int p) { return __uint_as_float(p & 0xFFFF0000u); }

__global__ void init_kernel(int* __restrict__ cnt, int n) {
    int i = blockIdx.x * 256 + threadIdx.x;
    if (i < n) cnt[i] = 0;
}

__global__ void count_kernel(const int* __restrict__ dst, int* __restrict__ cnt, int E) {
    int e = blockIdx.x * 256 + threadIdx.x;
    if (e < E) atomicAdd(&cnt[dst[e]], 1);
}

__global__ void dinv_kernel(const int* __restrict__ cnt, float* __restrict__ dinv, int n) {
    int i = blockIdx.x * 256 + threadIdx.x;
    if (i < n) dinv[i] = rsqrtf((float)cnt[i] + 1.0f);
}

// ---- hierarchical scan ----
__global__ __launch_bounds__(256) void scan_part_kernel(const int* __restrict__ cnt,
                                                        int* __restrict__ loc,
                                                        int* __restrict__ bsum, int n) {
    __shared__ int s[256];
    int t = threadIdx.x;
    int i0 = blockIdx.x * 1024 + t * 4;
    int v0 = (i0 + 0 < n) ? cnt[i0 + 0] : 0;
    int v1 = (i0 + 1 < n) ? cnt[i0 + 1] : 0;
    int v2 = (i0 + 2 < n) ? cnt[i0 + 2] : 0;
    int v3 = (i0 + 3 < n) ? cnt[i0 + 3] : 0;
    int tsum = v0 + v1 + v2 + v3;
    s[t] = tsum;
    __syncthreads();
    for (int d = 1; d < 256; d <<= 1) {
        int u = (t >= d) ? s[t - d] : 0;
        __syncthreads();
        s[t] += u;
        __syncthreads();
    }
    int base = s[t] - tsum;
    if (i0 + 0 < n) loc[i0 + 0] = base; base += v0;
    if (i0 + 1 < n) loc[i0 + 1] = base; base += v1;
    if (i0 + 2 < n) loc[i0 + 2] = base; base += v2;
    if (i0 + 3 < n) loc[i0 + 3] = base;
    if (t == 255) bsum[blockIdx.x] = s[255];
}

__global__ __launch_bounds__(256) void scan_top_kernel(int* __restrict__ bsum, int nb) {
    __shared__ int s[256];
    int t = threadIdx.x;
    int v = (t < nb) ? bsum[t] : 0;
    s[t] = v;
    __syncthreads();
    for (int d = 1; d < 256; d <<= 1) {
        int u = (t >= d) ? s[t - d] : 0;
        __syncthreads();
        s[t] += u;
        __syncthreads();
    }
    if (t < nb) bsum[t] = s[t] - v;
}

__global__ void scan_add_kernel(int* __restrict__ offs, int* __restrict__ cursor,
                                const int* __restrict__ bsum, int n, int E) {
    int i = blockIdx.x * 256 + threadIdx.x;
    if (i < n) {
        int off = offs[i] + bsum[i >> 10];
        offs[i] = off;
        cursor[i] = off;
    }
    if (i == 0) offs[n] = E;
}

// CSR fill with packed (src, dinv[src]) 8B stores.
__global__ void fill_kernel(const int* __restrict__ src, const int* __restrict__ dst,
                            const float* __restrict__ dinv, int* __restrict__ cursor,
                            int2* __restrict__ edat, int E) {
    int e = blockIdx.x * 256 + threadIdx.x;
    if (e < E) {
        int d = dst[e];
        int s = src[e];
        int p = atomicAdd(&cursor[d], 1);
        edat[p] = make_int2(s, __float_as_int(dinv[s]));
    }
}

// x0 fp32 -> (xh, xl) bf16 pair.
__global__ void split_x_kernel(const float* __restrict__ x, unsigned short* __restrict__ xh,
                               unsigned short* __restrict__ xl, int total) {
    int i = (blockIdx.x * 256 + threadIdx.x) * 4;
    if (i >= total) return;
    float4 v = *(const float4*)&x[i];
    ushort4 h4, l4;
    h4.x = f2bf(v.x); l4.x = f2bf(v.x - bf2f(h4.x));
    h4.y = f2bf(v.y); l4.y = f2bf(v.y - bf2f(h4.y));
    h4.z = f2bf(v.z); l4.z = f2bf(v.z - bf2f(h4.z));
    h4.w = f2bf(v.w); l4.w = f2bf(v.w - bf2f(h4.w));
    *(ushort4*)&xh[i] = h4;
    *(ushort4*)&xl[i] = l4;
}

// W [l][k][n] fp32 -> Wfh/Wfl in MFMA B-fragment order:
// group g = l*32 + t*4 + ks; elem = ((g*64) + q*16+ln)*8 + j
// holds W^T[t*16+ln][ks*32+q*8+j].
__global__ void wsplit_kernel(const float* __restrict__ Wall, unsigned short* __restrict__ Wfh,
                              unsigned short* __restrict__ Wfl, int total) {
    int idx = blockIdx.x * 256 + threadIdx.x;
    if (idx >= total) return;
    int l = idx >> 14;
    int rem = idx & 16383;
    int k = rem >> 7;
    int nn = rem & 127;
    float v = Wall[idx];
    unsigned short hi = f2bf(v);
    unsigned short lo = f2bf(v - bf2f(hi));
    int t = nn >> 4, ln = nn & 15;
    int ks = k >> 5, q = (k >> 3) & 3, j = k & 7;
    int o = ((((l << 5) | (t << 2) | ks) << 6) | (q << 4) | ln) * 8 + j;
    Wfh[o] = hi;
    Wfl[o] = lo;
}

// MFMA GEMM: h = (xh+xl) @ (Wh+Wl), bf16 store. 128 rows/block, 4 waves
// (32 rows = 2 m-tiles each). W hi+lo staged in 64KB LDS in fragment order
// (linear ds_read_b128, conflict-free). 3 products: ah*bh + al*bh + ah*bl.
__global__ __launch_bounds__(256) void gemm_mfma_kernel(
    const unsigned short* __restrict__ xh, const unsigned short* __restrict__ xl,
    const unsigned short* __restrict__ Wfh, const unsigned short* __restrict__ Wfl,
    unsigned short* __restrict__ h, int n) {
    __shared__ unsigned short ldsW[2][16384];  // 32KB hi + 32KB lo
    int tid = threadIdx.x;
    {
        const uint4* gh = (const uint4*)Wfh;
        const uint4* gl = (const uint4*)Wfl;
        uint4* sh = (uint4*)ldsW[0];
        uint4* sl = (uint4*)ldsW[1];
#pragma unroll
        for (int r = 0; r < 8; r++) {
            sh[tid + 256 * r] = gh[tid + 256 * r];
            sl[tid + 256 * r] = gl[tid + 256 * r];
        }
    }
    int wave = tid >> 6, lane = tid & 63;
    int q = lane >> 4, ln = lane & 15;
    int rowbase = blockIdx.x * 128 + wave * 32;
    // hoist A fragments: [m-tile][ks][hi/lo]
    bf16x8 A[2][4][2];
#pragma unroll
    for (int m = 0; m < 2; m++) {
        int ar = rowbase + m * 16 + ln;
        if (ar >= n) ar = n - 1;
        size_t base = (size_t)ar * GCN_DIM;
#pragma unroll
        for (int ks = 0; ks < 4; ks++) {
            A[m][ks][0] = *(const bf16x8*)&xh[base + ks * 32 + q * 8];
            A[m][ks][1] = *(const bf16x8*)&xl[base + ks * 32 + q * 8];
        }
    }
    __syncthreads();
#pragma unroll
    for (int t = 0; t < 8; t++) {
        f32x4 acc0 = (f32x4)(0.f), acc1 = (f32x4)(0.f);
#pragma unroll
        for (int ks = 0; ks < 4; ks++) {
            int fo = ((t * 4 + ks) * 64 + lane) * 8;
            bf16x8 bh = *(const bf16x8*)&ldsW[0][fo];
            bf16x8 bl = *(const bf16x8*)&ldsW[1][fo];
            acc0 = __builtin_amdgcn_mfma_f32_16x16x32_bf16(A[0][ks][0], bh, acc0, 0, 0, 0);
            acc1 = __builtin_amdgcn_mfma_f32_16x16x32_bf16(A[1][ks][0], bh, acc1, 0, 0, 0);
            acc0 = __builtin_amdgcn_mfma_f32_16x16x32_bf16(A[0][ks][1], bh, acc0, 0, 0, 0);
            acc1 = __builtin_amdgcn_mfma_f32_16x16x32_bf16(A[1][ks][1], bh, acc1, 0, 0, 0);
            acc0 = __builtin_amdgcn_mfma_f32_16x16x32_bf16(A[0][ks][0], bl, acc0, 0, 0, 0);
            acc1 = __builtin_amdgcn_mfma_f32_16x16x32_bf16(A[1][ks][0], bl, acc1, 0, 0, 0);
        }
#pragma unroll
        for (int m = 0; m < 2; m++) {
            f32x4 a = m ? acc1 : acc0;
#pragma unroll
            for (int r = 0; r < 4; r++) {
                int row = rowbase + m * 16 + q * 4 + r;
                if (row < n) h[(size_t)row * GCN_DIM + t * 16 + ln] = f2bf(a[r]);
            }
        }
    }
}

// Sliced aggregation: block handles 16 nodes x one 32-feature slice.
// slice = blockIdx%4 -> (assuming XCD = blockIdx%8) each XCD's L2 only
// caches a 3.2MB column-slice of h. Wave = 4 nodes x 16 lanes x 2 feats.
// Gather = one 64B line per (edge, slice). Unroll x4, dual accumulators.
__global__ void agg_kernel(const unsigned short* __restrict__ h,
                           const int2* __restrict__ edat,
                           const int* __restrict__ offs,
                           const float* __restrict__ dinv, const float* __restrict__ bias,
                           unsigned short* __restrict__ xh_out,
                           unsigned short* __restrict__ xl_out,
                           float* __restrict__ fout, int n) {
    int tid = threadIdx.x;
    int wave = tid >> 6, lane = tid & 63;
    int sub = lane >> 4, ln = lane & 15;
    int slice = blockIdx.x & 3;
    int node = (blockIdx.x >> 2) * 16 + wave * 4 + sub;
    if (node >= n) return;
    int co = slice * 32 + ln * 2;  // this lane's 2 features
    float di = dinv[node];
    unsigned int sp = *(const unsigned int*)&h[((size_t)node << 7) + co];
    float ax0 = di * bflo(sp);
    float ay0 = di * bfhi(sp);
    float ax1 = 0.f, ay1 = 0.f;
    int s = offs[node], e = offs[node + 1];
    int j = s;
    for (; j + 4 <= e; j += 4) {
        int2 e0 = edat[j], e1 = edat[j + 1], e2 = edat[j + 2], e3 = edat[j + 3];
        unsigned int p0 = *(const unsigned int*)&h[((size_t)e0.x << 7) + co];
        unsigned int p1 = *(const unsigned int*)&h[((size_t)e1.x << 7) + co];
        unsigned int p2 = *(const unsigned int*)&h[((size_t)e2.x << 7) + co];
        unsigned int p3 = *(const unsigned int*)&h[((size_t)e3.x << 7) + co];
        float w0 = __int_as_float(e0.y), w1 = __int_as_float(e1.y);
        float w2 = __int_as_float(e2.y), w3 = __int_as_float(e3.y);
        ax0 = fmaf(w0, bflo(p0), ax0); ay0 = fmaf(w0, bfhi(p0), ay0);
        ax1 = fmaf(w1, bflo(p1), ax1); ay1 = fmaf(w1, bfhi(p1), ay1);
        ax0 = fmaf(w2, bflo(p2), ax0); ay0 = fmaf(w2, bfhi(p2), ay0);
        ax1 = fmaf(w3, bflo(p3), ax1); ay1 = fmaf(w3, bfhi(p3), ay1);
    }
    for (; j < e; j++) {
        int2 e0 = edat[j];
        unsigned int p0 = *(const unsigned int*)&h[((size_t)e0.x << 7) + co];
        float w0 = __int_as_float(e0.y);
        ax0 = fmaf(w0, bflo(p0), ax0);
        ay0 = fmaf(w0, bfhi(p0), ay0);
    }
    float ax = ax0 + ax1, ay = ay0 + ay1;
    float2 b = *(const float2*)&bias[co];
    float rx = fmaxf(fmaf(di, ax, b.x), 0.f);
    float ry = fmaxf(fmaf(di, ay, b.y), 0.f);
    if (fout) {
        *(float2*)&fout[((size_t)node << 7) + co] = make_float2(rx, ry);
    } else {
        ushort2 hh, ll;
        hh.x = f2bf(rx); ll.x = f2bf(rx - bf2f(hh.x));
        hh.y = f2bf(ry); ll.y = f2bf(ry - bf2f(hh.y));
        *(ushort2*)&xh_out[((size_t)node << 7) + co] = hh;
        *(ushort2*)&xl_out[((size_t)node << 7) + co] = ll;
    }
}

extern "C" void kernel_launch(void* const* d_in, const int* in_sizes, int n_in,
                              void* d_out, int out_size, void* d_ws, size_t ws_size,
                              hipStream_t stream) {
    const float* x0    = (const float*)d_in[0];
    const int*   edges = (const int*)d_in[1];   // [2, E] int32: src then dst
    const float* Wall  = (const float*)d_in[2]; // [L, 128, 128]
    const float* Ball  = (const float*)d_in[3]; // [L, 128]
    float* out = (float*)d_out;

    const int n = in_sizes[0] / GCN_DIM;              // 50000
    const int E = in_sizes[1] / 2;                    // 800000
    const int L = in_sizes[2] / (GCN_DIM * GCN_DIM);  // 5

    // workspace layout
    int*   cnt    = (int*)d_ws;                        // n
    float* dinv   = (float*)(cnt + n);                 // n
    int*   offs   = (int*)(dinv + n);                  // n+16
    int*   cursor = offs + n + 16;                     // n
    int*   bsum   = cursor + n;                        // 64
    int2*  edat   = (int2*)(bsum + 64);                // E (8B each)
    unsigned short* h   = (unsigned short*)(edat + E); // n*128 bf16
    unsigned short* xh  = h  + (size_t)n * GCN_DIM;    // n*128 bf16
    unsigned short* xl  = xh + (size_t)n * GCN_DIM;    // n*128 bf16
    unsigned short* Wfh = xl + (size_t)n * GCN_DIM;    // L*16384 bf16 frag-order
    unsigned short* Wfl = Wfh + (size_t)L * GCN_DIM * GCN_DIM;

    const int* src = edges;
    const int* dst = edges + E;

    int nb_n = (n + 255) / 256;
    int nb_e = (E + 255) / 256;
    int nb_scan = (n + 1023) / 1024;

    init_kernel<<<nb_n, 256, 0, stream>>>(cnt, n);
    count_kernel<<<nb_e, 256, 0, stream>>>(dst, cnt, E);
    dinv_kernel<<<nb_n, 256, 0, stream>>>(cnt, dinv, n);
    scan_part_kernel<<<nb_scan, 256, 0, stream>>>(cnt, offs, bsum, n);
    scan_top_kernel<<<1, 256, 0, stream>>>(bsum, nb_scan);
    scan_add_kernel<<<nb_n, 256, 0, stream>>>(offs, cursor, bsum, n, E);
    fill_kernel<<<nb_e, 256, 0, stream>>>(src, dst, dinv, cursor, edat, E);

    int xtotal = n * GCN_DIM;
    split_x_kernel<<<(xtotal / 4 + 255) / 256, 256, 0, stream>>>(x0, xh, xl, xtotal);
    int wtotal = L * GCN_DIM * GCN_DIM;
    wsplit_kernel<<<(wtotal + 255) / 256, 256, 0, stream>>>(Wall, Wfh, Wfl, wtotal);

    int gemm_blocks = (n + 127) / 128;
    int agg_blocks  = ((n + 15) / 16) * 4;  // 16 nodes x 4 slices per block

    for (int l = 0; l < L; l++) {
        gemm_mfma_kernel<<<gemm_blocks, 256, 0, stream>>>(
            xh, xl, Wfh + (size_t)l * GCN_DIM * GCN_DIM, Wfl + (size_t)l * GCN_DIM * GCN_DIM, h, n);
        agg_kernel<<<agg_blocks, 256, 0, stream>>>(
            h, edat, offs, dinv, Ball + (size_t)l * GCN_DIM,
            xh, xl, (l == L - 1) ? out : nullptr, n);
    }
}